// Round 14
// baseline (570.134 us; speedup 1.0000x reference)
//
#include <hip/hip_runtime.h>
#include <math.h>

#define N_NODES 20000
#define M_PAD   20096   // 157 * 128
#define N_EDGES 320000
#define DIM_IN 768
#define DIM_H 512
#define NUM_GNNS 4
#define NEG_SLOPE 0.2f

#define GEMM_TILES 628        // (M_PAD/128) * (DIM_H/128) = 157*4
#define GEMM_GRID  632        // ceil to multiple of 8 for XCD swizzle

// sliced gather: 8 column slices (64 cols), slice = bid&7 -> XCD (round-robin).
#define SLC_GRID 5000

typedef __attribute__((ext_vector_type(8))) short short8;
typedef __attribute__((ext_vector_type(4))) float f32x4;

#define GPTR(p) (const __attribute__((address_space(1))) void*)(p)
#define LPTR(p) (__attribute__((address_space(3))) void*)(p)

__device__ __forceinline__ float bf2f(unsigned int lo16) {
  return __uint_as_float(lo16 << 16);
}
__device__ __forceinline__ unsigned short f2bf(float f) {
  unsigned int u = __float_as_uint(f);
  u += 0x7FFFu + ((u >> 16) & 1u);   // round-to-nearest-even
  return (unsigned short)(u >> 16);
}
__device__ __forceinline__ void unpack8(uint4 v, float* f) {
  f[0] = bf2f(v.x & 0xffffu); f[1] = bf2f(v.x >> 16);
  f[2] = bf2f(v.y & 0xffffu); f[3] = bf2f(v.y >> 16);
  f[4] = bf2f(v.z & 0xffffu); f[5] = bf2f(v.z >> 16);
  f[6] = bf2f(v.w & 0xffffu); f[7] = bf2f(v.w >> 16);
}
__device__ __forceinline__ uint4 pack8(const float* o) {
  uint4 pv;
  pv.x = (unsigned)f2bf(o[0]) | ((unsigned)f2bf(o[1]) << 16);
  pv.y = (unsigned)f2bf(o[2]) | ((unsigned)f2bf(o[3]) << 16);
  pv.z = (unsigned)f2bf(o[4]) | ((unsigned)f2bf(o[5]) << 16);
  pv.w = (unsigned)f2bf(o[6]) | ((unsigned)f2bf(o[7]) << 16);
  return pv;
}

// packed (idx,weight) record: idx in high 16 bits, fp16 weight in low 16.
__device__ __forceinline__ unsigned pack_rec(int idx, float w) {
  unsigned short hb = __builtin_bit_cast(unsigned short, (_Float16)w);
  return ((unsigned)idx << 16) | (unsigned)hb;
}
__device__ __forceinline__ float rec_w(unsigned r) {
  return (float)__builtin_bit_cast(_Float16, (unsigned short)(r & 0xffffu));
}

__device__ __forceinline__ float waveReduceSum(float v) {
#pragma unroll
  for (int off = 32; off > 0; off >>= 1) v += __shfl_xor(v, off, 64);
  return v;
}
__device__ __forceinline__ float waveReduceMax(float v) {
#pragma unroll
  for (int off = 32; off > 0; off >>= 1) v = fmaxf(v, __shfl_xor(v, off, 64));
  return v;
}

// ============ MFMA GEMM: 128x128 tile, 8 waves (512 thr), dbuf LDS, coalesced C ============
__global__ __launch_bounds__(512) void gemm_mfma_bf16(
    const unsigned short* __restrict__ A,
    const unsigned short* __restrict__ Bt,
    const float* __restrict__ bias,
    unsigned short* __restrict__ Cbf,
    int K) {
  int bid = blockIdx.x;
  int tile = (bid & 7) * (GEMM_GRID / 8) + (bid >> 3);
  if (tile >= GEMM_TILES) return;
  int brow = tile >> 2;   // 0..156
  int bcol = tile & 3;    // 0..3

  __shared__ __align__(16) unsigned short lds[4][128 * 32];
  int tid = threadIdx.x;
  int wave = tid >> 6, lane = tid & 63;
  int wm = wave >> 2, wn = wave & 3;   // 2 x 4 wave grid -> 64x32 per wave

  int rl = tid >> 2;
  int c4 = tid & 3;
  int kc = c4 ^ ((rl >> 1) & 3);
  const unsigned short* gA = A + (size_t)(brow * 128 + rl) * K + kc * 8;
  const unsigned short* gB = Bt + (size_t)(bcol * 128 + rl) * K + kc * 8;
  int stgoff = 16 * wave * 32;   // shorts

  int mrow = lane & 15;
  int q = lane >> 4;
  int swz = (q ^ ((mrow >> 1) & 3)) * 8;

  f32x4 acc[4][2];
#pragma unroll
  for (int i = 0; i < 4; ++i)
#pragma unroll
    for (int j = 0; j < 2; ++j) acc[i][j] = (f32x4)(0.f);

  int nk = K >> 5;
  {
    __builtin_amdgcn_global_load_lds(GPTR(gA), LPTR(lds[0] + stgoff), 16, 0, 0);
    __builtin_amdgcn_global_load_lds(GPTR(gB), LPTR(lds[2] + stgoff), 16, 0, 0);
  }
  __syncthreads();

  for (int t = 0; t < nk; ++t) {
    int cur = t & 1;
    if (t + 1 < nk) {
      int k0 = (t + 1) << 5;
      __builtin_amdgcn_global_load_lds(GPTR(gA + k0), LPTR(lds[cur ^ 1] + stgoff), 16, 0, 0);
      __builtin_amdgcn_global_load_lds(GPTR(gB + k0), LPTR(lds[2 + (cur ^ 1)] + stgoff), 16, 0, 0);
    }
    const short8* ra = (const short8*)(lds[cur] + (64 * wm + mrow) * 32 + swz);
    const short8* rb = (const short8*)(lds[2 + cur] + (32 * wn + mrow) * 32 + swz);
    short8 a[4], b[2];
#pragma unroll
    for (int u = 0; u < 4; ++u) a[u] = ra[u * 64];
#pragma unroll
    for (int u = 0; u < 2; ++u) b[u] = rb[u * 64];
#pragma unroll
    for (int mt = 0; mt < 4; ++mt)
#pragma unroll
      for (int nt = 0; nt < 2; ++nt)
        acc[mt][nt] = __builtin_amdgcn_mfma_f32_16x16x32_bf16(a[mt], b[nt], acc[mt][nt], 0, 0, 0);
    __syncthreads();
  }

  unsigned short* Cs = &lds[0][0];
  {
    float bv[2];
#pragma unroll
    for (int nt = 0; nt < 2; ++nt)
      bv[nt] = bias ? bias[bcol * 128 + 32 * wn + 16 * nt + mrow] : 0.f;
#pragma unroll
    for (int mt = 0; mt < 4; ++mt)
#pragma unroll
      for (int nt = 0; nt < 2; ++nt)
#pragma unroll
        for (int i = 0; i < 4; ++i) {
          int row = 64 * wm + 16 * mt + 4 * q + i;
          int col = 32 * wn + 16 * nt + mrow;
          Cs[row * 128 + col] = f2bf(acc[mt][nt][i] + bv[nt]);
        }
  }
  __syncthreads();
  int rr = tid >> 4, cb = (tid & 15) * 8;
#pragma unroll
  for (int it = 0; it < 4; ++it, rr += 32) {
    uint4 val = *(const uint4*)(Cs + rr * 128 + cb);
    *(uint4*)(Cbf + (size_t)(brow * 128 + rr) * DIM_H + bcol * 128 + cb) = val;
  }
}

// ================= conversions =================
__global__ void convert_feat(const float* __restrict__ feat, unsigned short* __restrict__ Abf) {
  int t = blockIdx.x * blockDim.x + threadIdx.x;
  const int CHUNKS = M_PAD * DIM_IN / 8;
  if (t >= CHUNKS) return;
  int row = t / (DIM_IN / 8);
  uint4 o;
  if (row < N_NODES) {
    const float4* p = (const float4*)(feat + (size_t)t * 8);
    float4 x = p[0], y = p[1];
    o.x = (unsigned)f2bf(x.x) | ((unsigned)f2bf(x.y) << 16);
    o.y = (unsigned)f2bf(x.z) | ((unsigned)f2bf(x.w) << 16);
    o.z = (unsigned)f2bf(y.x) | ((unsigned)f2bf(y.y) << 16);
    o.w = (unsigned)f2bf(y.z) | ((unsigned)f2bf(y.w) << 16);
  } else {
    o = make_uint4(0, 0, 0, 0);
  }
  ((uint4*)Abf)[t] = o;
}

// LDS-tiled transpose: in [R,C] f32 -> out [C,R] bf16. R,C multiples of 32.
__global__ __launch_bounds__(256) void transpose_bf16(const float* __restrict__ in,
                                                      unsigned short* __restrict__ out,
                                                      int R, int C) {
  __shared__ float tile[32][33];
  int tx = threadIdx.x, ty = threadIdx.y;
  size_t base = (size_t)blockIdx.z * R * C;
  int r0 = blockIdx.x * 32, c0 = blockIdx.y * 32;
#pragma unroll
  for (int i = 0; i < 4; ++i) {
    int r = r0 + ty + i * 8;
    tile[ty + i * 8][tx] = in[base + (size_t)r * C + c0 + tx];
  }
  __syncthreads();
#pragma unroll
  for (int i = 0; i < 4; ++i) {
    int c = c0 + ty + i * 8;
    out[base + (size_t)c * R + r0 + tx] = f2bf(tile[tx][ty + i * 8]);
  }
}

// ================= CSR build (dst -> src adjacency) =================
__global__ void count_edges(const int* __restrict__ dst, int* __restrict__ counts) {
  int k = blockIdx.x * blockDim.x + threadIdx.x;
  if (k < N_EDGES) atomicAdd(&counts[dst[k]], 1);
}

__global__ __launch_bounds__(1024) void scan_kernel(const int* __restrict__ counts,
                                                    int* __restrict__ indptr) {
  __shared__ int part[1024];
  int tid = threadIdx.x;
  const int CH = (N_NODES + 1023) / 1024;
  int base = tid * CH;
  int s = 0;
  for (int i = 0; i < CH; ++i) {
    int idx = base + i;
    if (idx < N_NODES) s += counts[idx];
  }
  part[tid] = s;
  __syncthreads();
  for (int off = 1; off < 1024; off <<= 1) {
    int v = (tid >= off) ? part[tid - off] : 0;
    __syncthreads();
    part[tid] += v;
    __syncthreads();
  }
  int run = (tid == 0) ? 0 : part[tid - 1];
  for (int i = 0; i < CH; ++i) {
    int idx = base + i;
    if (idx < N_NODES) {
      indptr[idx] = run;
      run += counts[idx];
      if (idx == N_NODES - 1) indptr[N_NODES] = run;
    }
  }
}

__global__ void fill_adj(const int* __restrict__ src, const int* __restrict__ dst,
                         const int* __restrict__ indptr, int* __restrict__ cursor,
                         int* __restrict__ adjsrc) {
  int k = blockIdx.x * blockDim.x + threadIdx.x;
  if (k < N_EDGES) {
    int d = dst[k];
    int pos = atomicAdd(&cursor[d], 1);
    adjsrc[indptr[d] + pos] = src[k];
  }
}

// ============ window-local degree sort (256-node windows, LDS counting sort) ============
__global__ __launch_bounds__(256) void build_perm_win(const int* __restrict__ counts,
                                                      int* __restrict__ perm) {
  __shared__ int hist[64];
  __shared__ int basec[64];
  int tid = threadIdx.x;
  int v0 = blockIdx.x * 256;
  int n = min(256, N_NODES - v0);
  if (tid < 64) hist[tid] = 0;
  __syncthreads();
  int b = 0;
  if (tid < n) {
    b = min(counts[v0 + tid], 63);
    atomicAdd(&hist[b], 1);
  }
  __syncthreads();
  if (tid == 0) {
    int run = 0;
#pragma unroll
    for (int i = 0; i < 64; ++i) { basec[i] = run; run += hist[i]; }
  }
  __syncthreads();
  if (tid < n) {
    int pos = atomicAdd(&basec[b], 1);
    perm[v0 + pos] = v0 + tid;
  }
}

// ============ weight-1 packed records for propagation hops ============
__global__ void pack_ones(const int* __restrict__ adjsrc, unsigned* __restrict__ apairs) {
  int k = blockIdx.x * blockDim.x + threadIdx.x;
  if (k < N_EDGES) apairs[k] = ((unsigned)adjsrc[k] << 16) | 0x3C00u;  // fp16 1.0
}

// ================= el/er from bf16 z =================
__global__ __launch_bounds__(256) void eler_bf(const unsigned short* __restrict__ zbf,
                                               const float* __restrict__ al,
                                               const float* __restrict__ ar,
                                               float* __restrict__ el, float* __restrict__ er) {
  int wid = (blockIdx.x * blockDim.x + threadIdx.x) >> 6;
  int lane = threadIdx.x & 63;
  if (wid >= N_NODES) return;
  uint4 zv = ((const uint4*)(zbf + (size_t)wid * DIM_H))[lane];
  float z[8];
  unpack8(zv, z);
  const float4* al4 = (const float4*)(al + lane * 8);
  const float4* ar4 = (const float4*)(ar + lane * 8);
  float4 a0 = al4[0], a1 = al4[1], r0 = ar4[0], r1 = ar4[1];
  float sl = z[0] * a0.x + z[1] * a0.y + z[2] * a0.z + z[3] * a0.w +
             z[4] * a1.x + z[5] * a1.y + z[6] * a1.z + z[7] * a1.w;
  float sr = z[0] * r0.x + z[1] * r0.y + z[2] * r0.z + z[3] * r0.w +
             z[4] * r1.x + z[5] * r1.y + z[6] * r1.z + z[7] * r1.w;
  sl = waveReduceSum(sl);
  sr = waveReduceSum(sr);
  if (lane == 0) { el[wid] = sl; er[wid] = sr; }
}

// ================= edge softmax -> packed uint32 (idx<<16 | fp16 alpha) records =========
__global__ __launch_bounds__(256) void edge_softmax_alpha(
    const float* __restrict__ el, const float* __restrict__ er,
    const int* __restrict__ indptr, const int* __restrict__ adjsrc,
    float* __restrict__ alpha, unsigned* __restrict__ apairs) {
  int v = (blockIdx.x * blockDim.x + threadIdx.x) >> 6;
  int lane = threadIdx.x & 63;
  if (v >= N_NODES) return;
  int begin = indptr[v], end = indptr[v + 1];
  float er_v = er[v];

  float m = -INFINITY;
  for (int j = begin + lane; j < end; j += 64) {
    float e = el[adjsrc[j]] + er_v;
    e = (e >= 0.f) ? e : NEG_SLOPE * e;
    alpha[j] = e;
    m = fmaxf(m, e);
  }
  m = waveReduceMax(m);

  float ss = 0.f;
  for (int j = begin + lane; j < end; j += 64) {
    float ex = __expf(alpha[j] - m);
    alpha[j] = ex;
    ss += ex;
  }
  float denom = waveReduceSum(ss);
  float inv = (end > begin) ? 1.f / denom : 0.f;

  for (int j = begin + lane; j < end; j += 64)
    apairs[j] = pack_rec(adjsrc[j], alpha[j] * inv);
}

// ========== XCD-sliced gather: window-sorted slot-per-node, 4B records, =============
// ========== 2-deep z-PIPELINE (issue batch t+1 gathers before batch t fma) ==========
// Steady state: every z-gather has a full batch of VALU (~380cy) between issue and
// first use -> L2 latency hidden within the wave, not just by TLP (which measured
// Occupancy 28% can't supply). Records prefetched 2 batches ahead. All reads beyond
// a node's edge range hit padded/garbage memory with weight 0 and index clamped.
__global__ __launch_bounds__(256) void gather_slc(
    const unsigned short* __restrict__ zin, const unsigned* __restrict__ apairs,
    const int* __restrict__ indptr, const int* __restrict__ perm,
    const float* __restrict__ bias, int self_term,
    unsigned short* __restrict__ out_bf, float* __restrict__ out_f32) {
  int slice = blockIdx.x & 7;
  int grp = blockIdx.x >> 3;                    // 0..624
  int wave = threadIdx.x >> 6, lane = threadIdx.x & 63;
  int slot = lane >> 3, sub = lane & 7;
  int vidx = grp * 32 + wave * 8 + slot;
  int v = perm[vidx];                           // window-degree-sorted node
  unsigned cbyte = (unsigned)(slice * 128 + sub * 16);
  const char* zb = (const char*)zin;
  const char* pb = (const char*)apairs;

  int b = indptr[v];
  int deg = indptr[v + 1] - b;
  int md = deg;                                 // max degree over the 8 slots (~deg)
  md = max(md, __shfl_xor(md, 8, 64));
  md = max(md, __shfl_xor(md, 16, 64));
  md = max(md, __shfl_xor(md, 32, 64));

  float acc[8];
  if (self_term) {
    uint4 sz = *(const uint4*)(zb + (((unsigned)v) << 10) + cbyte);
    unpack8(sz, acc);
  } else {
#pragma unroll
    for (int i = 0; i < 8; ++i) acc[i] = 0.f;
  }

  const unsigned NMAX = (unsigned)(N_NODES - 1);
  unsigned ab = ((unsigned)b) << 2;             // 4B records
  // records for batch 0 and batch 1 (reads past range are masked later)
  uint4 ra0 = *(const uint4*)(pb + ab);
  uint4 ra1 = *(const uint4*)(pb + ab + 16);
  uint4 rb0 = *(const uint4*)(pb + ab + 32);
  uint4 rb1 = *(const uint4*)(pb + ab + 48);
  // z loads for batch 0
  uint4 za_[8];
  {
    unsigned rr[8] = {ra0.x, ra0.y, ra0.z, ra0.w, ra1.x, ra1.y, ra1.z, ra1.w};
#pragma unroll
    for (int u = 0; u < 8; ++u)
      za_[u] = *(const uint4*)(zb + ((size_t)min(rr[u] >> 16, NMAX) << 10) + cbyte);
  }

#pragma nounroll
  for (int t = 0; t < md; t += 8) {
    // prefetch records for batch t+16 (wave-uniform branch)
    uint4 rc0, rc1;
    if (t + 16 < md) {
      rc0 = *(const uint4*)(pb + ab + 64);
      rc1 = *(const uint4*)(pb + ab + 80);
    } else {
      rc0 = rb0; rc1 = rb1;
    }
    // issue z loads for batch t+8 BEFORE consuming batch t
    uint4 zn_[8];
    if (t + 8 < md) {
      unsigned rr[8] = {rb0.x, rb0.y, rb0.z, rb0.w, rb1.x, rb1.y, rb1.z, rb1.w};
#pragma unroll
      for (int u = 0; u < 8; ++u)
        zn_[u] = *(const uint4*)(zb + ((size_t)min(rr[u] >> 16, NMAX) << 10) + cbyte);
    } else {
#pragma unroll
      for (int u = 0; u < 8; ++u) zn_[u] = za_[u];
    }
    // consume batch t
    {
      unsigned rr[8] = {ra0.x, ra0.y, ra0.z, ra0.w, ra1.x, ra1.y, ra1.z, ra1.w};
      int rem = deg - t;
#pragma unroll
      for (int u = 0; u < 8; ++u) {
        float wv = (u < rem) ? rec_w(rr[u]) : 0.f;
        float f[8];
        unpack8(za_[u], f);
#pragma unroll
        for (int i = 0; i < 8; ++i) acc[i] = fmaf(wv, f[i], acc[i]);
      }
    }
    // shift pipeline
#pragma unroll
    for (int u = 0; u < 8; ++u) za_[u] = zn_[u];
    ra0 = rb0; ra1 = rb1; rb0 = rc0; rb1 = rc1;
    ab += 32;
  }

  if (bias) {
    const float4* b4 = (const float4*)(bias + slice * 64 + sub * 8);
    float4 b0 = b4[0], b1 = b4[1];
    acc[0] += b0.x; acc[1] += b0.y; acc[2] += b0.z; acc[3] += b0.w;
    acc[4] += b1.x; acc[5] += b1.y; acc[6] += b1.z; acc[7] += b1.w;
  }
  if (out_bf) {
    uint4 pv = pack8(acc);
    *(uint4*)((char*)out_bf + (((unsigned)v) << 10) + cbyte) = pv;
  } else {
    char* p = (char*)out_f32 + (((unsigned)v) << 11) + cbyte * 2;
    *(f32x4*)p = (f32x4){acc[0], acc[1], acc[2], acc[3]};
    *(f32x4*)(p + 16) = (f32x4){acc[4], acc[5], acc[6], acc[7]};
  }
}

// ================= launch =================
extern "C" void kernel_launch(void* const* d_in, const int* in_sizes, int n_in,
                              void* d_out, int out_size, void* d_ws, size_t ws_size,
                              hipStream_t stream) {
  const float* feat = (const float*)d_in[0];
  const float* fc_W = (const float*)d_in[1];
  const float* fc_b = (const float*)d_in[2];
  const float* gat_W = (const float*)d_in[3];
  const float* gat_al = (const float*)d_in[4];
  const float* gat_ar = (const float*)d_in[5];
  const float* gat_b = (const float*)d_in[6];
  // d_in[7] = beta unused (reference returns Z_prev)
  const int* src = (const int*)d_in[8];
  const int* dst = (const int*)d_in[9];
  float* out = (float*)d_out;

  char* w = (char*)d_ws;
  auto alloc = [&](size_t bytes) {
    char* p = w;
    w += (bytes + 255) & ~(size_t)255;
    return p;
  };
  unsigned short* hbf   = (unsigned short*)alloc((size_t)M_PAD * DIM_H * 2);
  unsigned short* fcWt  = (unsigned short*)alloc((size_t)DIM_H * DIM_IN * 2);
  unsigned short* gatWt = (unsigned short*)alloc((size_t)NUM_GNNS * DIM_H * DIM_H * 2);
  float* el    = (float*)alloc((size_t)N_NODES * 4);
  float* er    = (float*)alloc((size_t)N_NODES * 4);
  int* counts  = (int*)alloc((size_t)2 * N_NODES * 4);   // counts+cursor contiguous
  int* cursor  = counts + N_NODES;
  int* indptr  = (int*)alloc((size_t)(N_NODES + 1) * 4);
  int* adjsrc  = (int*)alloc((size_t)(N_EDGES + 64) * 4); // +pad for overshoot reads
  int* perm    = (int*)alloc((size_t)N_NODES * 4);
  char* uni = alloc((size_t)M_PAD * DIM_IN * 2);   // 30.9 MB union region
  unsigned short* Abf = (unsigned short*)uni;      // live: convert + first GEMM only
  float* alpha = (float*)uni;                      // live: softmax scratch per layer (1.28 MB)
  unsigned short* Z1  = (unsigned short*)uni;      // live: propagation ping buffer (20.6 MB)
  // packed 4B records at uni+20.6MB: disjoint from Z1 AND from alpha
  unsigned* apairs = (unsigned*)(uni + (size_t)M_PAD * DIM_H * 2);  // 1.28 MB + pad
  unsigned short* zbf = (unsigned short*)d_out;

  // ---- CSR build + window-local degree sort ----
  hipMemsetAsync(counts, 0, sizeof(int) * 2 * N_NODES, stream);
  count_edges<<<(N_EDGES + 255) / 256, 256, 0, stream>>>(dst, counts);
  scan_kernel<<<1, 1024, 0, stream>>>(counts, indptr);
  fill_adj<<<(N_EDGES + 255) / 256, 256, 0, stream>>>(src, dst, indptr, cursor, adjsrc);
  build_perm_win<<<(N_NODES + 255) / 256, 256, 0, stream>>>(counts, perm);

  // ---- bf16 prep ----
  convert_feat<<<(M_PAD * DIM_IN / 8 + 255) / 256, 256, 0, stream>>>(feat, Abf);
  transpose_bf16<<<dim3(DIM_IN / 32, DIM_H / 32, 1), dim3(32, 8), 0, stream>>>(fc_W, fcWt, DIM_IN, DIM_H);
  transpose_bf16<<<dim3(DIM_H / 32, DIM_H / 32, NUM_GNNS), dim3(32, 8), 0, stream>>>(gat_W, gatWt, DIM_H, DIM_H);

  gemm_mfma_bf16<<<GEMM_GRID, 512, 0, stream>>>(Abf, fcWt, fc_b, hbf, DIM_IN);

  int nwaveblocks = (N_NODES * 64 + 255) / 256;
  for (int l = 0; l < NUM_GNNS; ++l) {
    gemm_mfma_bf16<<<GEMM_GRID, 512, 0, stream>>>(hbf, gatWt + (size_t)l * DIM_H * DIM_H,
                                                  nullptr, zbf, DIM_H);
    eler_bf<<<nwaveblocks, 256, 0, stream>>>(zbf, gat_al + (size_t)l * DIM_H,
                                             gat_ar + (size_t)l * DIM_H, el, er);
    edge_softmax_alpha<<<nwaveblocks, 256, 0, stream>>>(el, er, indptr, adjsrc, alpha, apairs);
    gather_slc<<<SLC_GRID, 256, 0, stream>>>(
        zbf, apairs, indptr, perm, gat_b + (size_t)l * DIM_H, 0, hbf, nullptr);
  }

  // ---- 3 propagation hops: weight-1 packed records, same gather ----
  pack_ones<<<(N_EDGES + 255) / 256, 256, 0, stream>>>(adjsrc, apairs);
  gather_slc<<<SLC_GRID, 256, 0, stream>>>(hbf, apairs, indptr, perm, nullptr, 1, Z1, nullptr);
  gather_slc<<<SLC_GRID, 256, 0, stream>>>(Z1, apairs, indptr, perm, nullptr, 1, hbf, nullptr);
  gather_slc<<<SLC_GRID, 256, 0, stream>>>(hbf, apairs, indptr, perm, nullptr, 1, nullptr, out);
}

// Round 15
// 550.683 us; speedup vs baseline: 1.0353x; 1.0353x over previous
//
#include <hip/hip_runtime.h>
#include <math.h>

#define N_NODES 20000
#define M_PAD   20096   // 157 * 128
#define N_EDGES 320000
#define DIM_IN 768
#define DIM_H 512
#define NUM_GNNS 4
#define NEG_SLOPE 0.2f

#define GEMM_TILES 628        // (M_PAD/128) * (DIM_H/128) = 157*4
#define GEMM_GRID  632        // ceil to multiple of 8 for XCD swizzle

// sliced gather: 8 column slices (64 cols), slice = bid&7 -> XCD (round-robin).
#define SLC_GRID 5000

typedef __attribute__((ext_vector_type(8))) short short8;
typedef __attribute__((ext_vector_type(4))) float f32x4;

#define GPTR(p) (const __attribute__((address_space(1))) void*)(p)
#define LPTR(p) (__attribute__((address_space(3))) void*)(p)

__device__ __forceinline__ float bf2f(unsigned int lo16) {
  return __uint_as_float(lo16 << 16);
}
__device__ __forceinline__ unsigned short f2bf(float f) {
  unsigned int u = __float_as_uint(f);
  u += 0x7FFFu + ((u >> 16) & 1u);   // round-to-nearest-even
  return (unsigned short)(u >> 16);
}
__device__ __forceinline__ void unpack8(uint4 v, float* f) {
  f[0] = bf2f(v.x & 0xffffu); f[1] = bf2f(v.x >> 16);
  f[2] = bf2f(v.y & 0xffffu); f[3] = bf2f(v.y >> 16);
  f[4] = bf2f(v.z & 0xffffu); f[5] = bf2f(v.z >> 16);
  f[6] = bf2f(v.w & 0xffffu); f[7] = bf2f(v.w >> 16);
}
__device__ __forceinline__ uint4 pack8(const float* o) {
  uint4 pv;
  pv.x = (unsigned)f2bf(o[0]) | ((unsigned)f2bf(o[1]) << 16);
  pv.y = (unsigned)f2bf(o[2]) | ((unsigned)f2bf(o[3]) << 16);
  pv.z = (unsigned)f2bf(o[4]) | ((unsigned)f2bf(o[5]) << 16);
  pv.w = (unsigned)f2bf(o[6]) | ((unsigned)f2bf(o[7]) << 16);
  return pv;
}

// packed (idx,weight) record: idx in high 16 bits, fp16 weight in low 16.
__device__ __forceinline__ unsigned pack_rec(int idx, float w) {
  unsigned short hb = __builtin_bit_cast(unsigned short, (_Float16)w);
  return ((unsigned)idx << 16) | (unsigned)hb;
}
__device__ __forceinline__ float rec_w(unsigned r) {
  return (float)__builtin_bit_cast(_Float16, (unsigned short)(r & 0xffffu));
}

__device__ __forceinline__ float waveReduceSum(float v) {
#pragma unroll
  for (int off = 32; off > 0; off >>= 1) v += __shfl_xor(v, off, 64);
  return v;
}
__device__ __forceinline__ float waveReduceMax(float v) {
#pragma unroll
  for (int off = 32; off > 0; off >>= 1) v = fmaxf(v, __shfl_xor(v, off, 64));
  return v;
}

// ============ MFMA GEMM: 128x128 tile, 8 waves (512 thr), dbuf LDS, coalesced C ============
__global__ __launch_bounds__(512) void gemm_mfma_bf16(
    const unsigned short* __restrict__ A,
    const unsigned short* __restrict__ Bt,
    const float* __restrict__ bias,
    unsigned short* __restrict__ Cbf,
    int K) {
  int bid = blockIdx.x;
  int tile = (bid & 7) * (GEMM_GRID / 8) + (bid >> 3);
  if (tile >= GEMM_TILES) return;
  int brow = tile >> 2;   // 0..156
  int bcol = tile & 3;    // 0..3

  __shared__ __align__(16) unsigned short lds[4][128 * 32];
  int tid = threadIdx.x;
  int wave = tid >> 6, lane = tid & 63;
  int wm = wave >> 2, wn = wave & 3;   // 2 x 4 wave grid -> 64x32 per wave

  int rl = tid >> 2;
  int c4 = tid & 3;
  int kc = c4 ^ ((rl >> 1) & 3);
  const unsigned short* gA = A + (size_t)(brow * 128 + rl) * K + kc * 8;
  const unsigned short* gB = Bt + (size_t)(bcol * 128 + rl) * K + kc * 8;
  int stgoff = 16 * wave * 32;   // shorts

  int mrow = lane & 15;
  int q = lane >> 4;
  int swz = (q ^ ((mrow >> 1) & 3)) * 8;

  f32x4 acc[4][2];
#pragma unroll
  for (int i = 0; i < 4; ++i)
#pragma unroll
    for (int j = 0; j < 2; ++j) acc[i][j] = (f32x4)(0.f);

  int nk = K >> 5;
  {
    __builtin_amdgcn_global_load_lds(GPTR(gA), LPTR(lds[0] + stgoff), 16, 0, 0);
    __builtin_amdgcn_global_load_lds(GPTR(gB), LPTR(lds[2] + stgoff), 16, 0, 0);
  }
  __syncthreads();

  for (int t = 0; t < nk; ++t) {
    int cur = t & 1;
    if (t + 1 < nk) {
      int k0 = (t + 1) << 5;
      __builtin_amdgcn_global_load_lds(GPTR(gA + k0), LPTR(lds[cur ^ 1] + stgoff), 16, 0, 0);
      __builtin_amdgcn_global_load_lds(GPTR(gB + k0), LPTR(lds[2 + (cur ^ 1)] + stgoff), 16, 0, 0);
    }
    const short8* ra = (const short8*)(lds[cur] + (64 * wm + mrow) * 32 + swz);
    const short8* rb = (const short8*)(lds[2 + cur] + (32 * wn + mrow) * 32 + swz);
    short8 a[4], b[2];
#pragma unroll
    for (int u = 0; u < 4; ++u) a[u] = ra[u * 64];
#pragma unroll
    for (int u = 0; u < 2; ++u) b[u] = rb[u * 64];
#pragma unroll
    for (int mt = 0; mt < 4; ++mt)
#pragma unroll
      for (int nt = 0; nt < 2; ++nt)
        acc[mt][nt] = __builtin_amdgcn_mfma_f32_16x16x32_bf16(a[mt], b[nt], acc[mt][nt], 0, 0, 0);
    __syncthreads();
  }

  unsigned short* Cs = &lds[0][0];
  {
    float bv[2];
#pragma unroll
    for (int nt = 0; nt < 2; ++nt)
      bv[nt] = bias ? bias[bcol * 128 + 32 * wn + 16 * nt + mrow] : 0.f;
#pragma unroll
    for (int mt = 0; mt < 4; ++mt)
#pragma unroll
      for (int nt = 0; nt < 2; ++nt)
#pragma unroll
        for (int i = 0; i < 4; ++i) {
          int row = 64 * wm + 16 * mt + 4 * q + i;
          int col = 32 * wn + 16 * nt + mrow;
          Cs[row * 128 + col] = f2bf(acc[mt][nt][i] + bv[nt]);
        }
  }
  __syncthreads();
  int rr = tid >> 4, cb = (tid & 15) * 8;
#pragma unroll
  for (int it = 0; it < 4; ++it, rr += 32) {
    uint4 val = *(const uint4*)(Cs + rr * 128 + cb);
    *(uint4*)(Cbf + (size_t)(brow * 128 + rr) * DIM_H + bcol * 128 + cb) = val;
  }
}

// ================= conversions =================
__global__ void convert_feat(const float* __restrict__ feat, unsigned short* __restrict__ Abf) {
  int t = blockIdx.x * blockDim.x + threadIdx.x;
  const int CHUNKS = M_PAD * DIM_IN / 8;
  if (t >= CHUNKS) return;
  int row = t / (DIM_IN / 8);
  uint4 o;
  if (row < N_NODES) {
    const float4* p = (const float4*)(feat + (size_t)t * 8);
    float4 x = p[0], y = p[1];
    o.x = (unsigned)f2bf(x.x) | ((unsigned)f2bf(x.y) << 16);
    o.y = (unsigned)f2bf(x.z) | ((unsigned)f2bf(x.w) << 16);
    o.z = (unsigned)f2bf(y.x) | ((unsigned)f2bf(y.y) << 16);
    o.w = (unsigned)f2bf(y.z) | ((unsigned)f2bf(y.w) << 16);
  } else {
    o = make_uint4(0, 0, 0, 0);
  }
  ((uint4*)Abf)[t] = o;
}

// LDS-tiled transpose: in [R,C] f32 -> out [C,R] bf16. R,C multiples of 32.
__global__ __launch_bounds__(256) void transpose_bf16(const float* __restrict__ in,
                                                      unsigned short* __restrict__ out,
                                                      int R, int C) {
  __shared__ float tile[32][33];
  int tx = threadIdx.x, ty = threadIdx.y;
  size_t base = (size_t)blockIdx.z * R * C;
  int r0 = blockIdx.x * 32, c0 = blockIdx.y * 32;
#pragma unroll
  for (int i = 0; i < 4; ++i) {
    int r = r0 + ty + i * 8;
    tile[ty + i * 8][tx] = in[base + (size_t)r * C + c0 + tx];
  }
  __syncthreads();
#pragma unroll
  for (int i = 0; i < 4; ++i) {
    int c = c0 + ty + i * 8;
    out[base + (size_t)c * R + r0 + tx] = f2bf(tile[tx][ty + i * 8]);
  }
}

// ================= CSR build (dst -> src adjacency) =================
__global__ void count_edges(const int* __restrict__ dst, int* __restrict__ counts) {
  int k = blockIdx.x * blockDim.x + threadIdx.x;
  if (k < N_EDGES) atomicAdd(&counts[dst[k]], 1);
}

__global__ __launch_bounds__(1024) void scan_kernel(const int* __restrict__ counts,
                                                    int* __restrict__ indptr) {
  __shared__ int part[1024];
  int tid = threadIdx.x;
  const int CH = (N_NODES + 1023) / 1024;
  int base = tid * CH;
  int s = 0;
  for (int i = 0; i < CH; ++i) {
    int idx = base + i;
    if (idx < N_NODES) s += counts[idx];
  }
  part[tid] = s;
  __syncthreads();
  for (int off = 1; off < 1024; off <<= 1) {
    int v = (tid >= off) ? part[tid - off] : 0;
    __syncthreads();
    part[tid] += v;
    __syncthreads();
  }
  int run = (tid == 0) ? 0 : part[tid - 1];
  for (int i = 0; i < CH; ++i) {
    int idx = base + i;
    if (idx < N_NODES) {
      indptr[idx] = run;
      run += counts[idx];
      if (idx == N_NODES - 1) indptr[N_NODES] = run;
    }
  }
}

// fill adjacency AND weight-1 packed records in one pass (pack_ones folded in; the
// onerec buffer lives OUTSIDE the uni region so later Abf writes can't clobber it).
__global__ void fill_adj(const int* __restrict__ src, const int* __restrict__ dst,
                         const int* __restrict__ indptr, int* __restrict__ cursor,
                         int* __restrict__ adjsrc, unsigned* __restrict__ onerec) {
  int k = blockIdx.x * blockDim.x + threadIdx.x;
  if (k < N_EDGES) {
    int d = dst[k];
    int s = src[k];
    int pos = atomicAdd(&cursor[d], 1);
    int j = indptr[d] + pos;
    adjsrc[j] = s;
    onerec[j] = ((unsigned)s << 16) | 0x3C00u;   // fp16 1.0
  }
}

// ============ window-local degree sort (256-node windows, LDS counting sort) ============
__global__ __launch_bounds__(256) void build_perm_win(const int* __restrict__ counts,
                                                      int* __restrict__ perm) {
  __shared__ int hist[64];
  __shared__ int basec[64];
  int tid = threadIdx.x;
  int v0 = blockIdx.x * 256;
  int n = min(256, N_NODES - v0);
  if (tid < 64) hist[tid] = 0;
  __syncthreads();
  int b = 0;
  if (tid < n) {
    b = min(counts[v0 + tid], 63);
    atomicAdd(&hist[b], 1);
  }
  __syncthreads();
  if (tid == 0) {
    int run = 0;
#pragma unroll
    for (int i = 0; i < 64; ++i) { basec[i] = run; run += hist[i]; }
  }
  __syncthreads();
  if (tid < n) {
    int pos = atomicAdd(&basec[b], 1);
    perm[v0 + pos] = v0 + tid;
  }
}

// ================= el/er from bf16 z =================
__global__ __launch_bounds__(256) void eler_bf(const unsigned short* __restrict__ zbf,
                                               const float* __restrict__ al,
                                               const float* __restrict__ ar,
                                               float* __restrict__ el, float* __restrict__ er) {
  int wid = (blockIdx.x * blockDim.x + threadIdx.x) >> 6;
  int lane = threadIdx.x & 63;
  if (wid >= N_NODES) return;
  uint4 zv = ((const uint4*)(zbf + (size_t)wid * DIM_H))[lane];
  float z[8];
  unpack8(zv, z);
  const float4* al4 = (const float4*)(al + lane * 8);
  const float4* ar4 = (const float4*)(ar + lane * 8);
  float4 a0 = al4[0], a1 = al4[1], r0 = ar4[0], r1 = ar4[1];
  float sl = z[0] * a0.x + z[1] * a0.y + z[2] * a0.z + z[3] * a0.w +
             z[4] * a1.x + z[5] * a1.y + z[6] * a1.z + z[7] * a1.w;
  float sr = z[0] * r0.x + z[1] * r0.y + z[2] * r0.z + z[3] * r0.w +
             z[4] * r1.x + z[5] * r1.y + z[6] * r1.z + z[7] * r1.w;
  sl = waveReduceSum(sl);
  sr = waveReduceSum(sr);
  if (lane == 0) { el[wid] = sl; er[wid] = sr; }
}

// ================= edge softmax -> packed uint32 (idx<<16 | fp16 alpha) records =========
__global__ __launch_bounds__(256) void edge_softmax_alpha(
    const float* __restrict__ el, const float* __restrict__ er,
    const int* __restrict__ indptr, const int* __restrict__ adjsrc,
    float* __restrict__ alpha, unsigned* __restrict__ apairs) {
  int v = (blockIdx.x * blockDim.x + threadIdx.x) >> 6;
  int lane = threadIdx.x & 63;
  if (v >= N_NODES) return;
  int begin = indptr[v], end = indptr[v + 1];
  float er_v = er[v];

  float m = -INFINITY;
  for (int j = begin + lane; j < end; j += 64) {
    float e = el[adjsrc[j]] + er_v;
    e = (e >= 0.f) ? e : NEG_SLOPE * e;
    alpha[j] = e;
    m = fmaxf(m, e);
  }
  m = waveReduceMax(m);

  float ss = 0.f;
  for (int j = begin + lane; j < end; j += 64) {
    float ex = __expf(alpha[j] - m);
    alpha[j] = ex;
    ss += ex;
  }
  float denom = waveReduceSum(ss);
  float inv = (end > begin) ? 1.f / denom : 0.f;

  for (int j = begin + lane; j < end; j += 64)
    apairs[j] = pack_rec(adjsrc[j], alpha[j] * inv);
}

// ========== XCD-sliced gather: slot-per-node (window-sorted), 4B records, prefetch =======
// (R13 champion form: single-batch record prefetch, no z-pipeline -- R14's 2-deep
//  z-pipeline regressed: register-shift VALU + VGPR pressure with only ~2-3
//  batches per node.)
__global__ __launch_bounds__(256) void gather_slc(
    const unsigned short* __restrict__ zin, const unsigned* __restrict__ apairs,
    const int* __restrict__ indptr, const int* __restrict__ perm,
    const float* __restrict__ bias, int self_term,
    unsigned short* __restrict__ out_bf, float* __restrict__ out_f32) {
  int slice = blockIdx.x & 7;
  int grp = blockIdx.x >> 3;                    // 0..624
  int wave = threadIdx.x >> 6, lane = threadIdx.x & 63;
  int slot = lane >> 3, sub = lane & 7;
  int vidx = grp * 32 + wave * 8 + slot;
  int v = perm[vidx];                           // window-degree-sorted node
  unsigned cbyte = (unsigned)(slice * 128 + sub * 16);
  const char* zb = (const char*)zin;
  const char* pb = (const char*)apairs;

  int b = indptr[v];
  int deg = indptr[v + 1] - b;
  int md = deg;                                 // max degree over the 8 slots (~deg now)
  md = max(md, __shfl_xor(md, 8, 64));
  md = max(md, __shfl_xor(md, 16, 64));
  md = max(md, __shfl_xor(md, 32, 64));

  float acc[8];
  if (self_term) {
    uint4 sz = *(const uint4*)(zb + (((unsigned)v) << 10) + cbyte);
    unpack8(sz, acc);
  } else {
#pragma unroll
    for (int i = 0; i < 8; ++i) acc[i] = 0.f;
  }

  const unsigned NMAX = (unsigned)(N_NODES - 1);
  unsigned ab = ((unsigned)b) << 2;             // 4B records
  uint4 ra0 = *(const uint4*)(pb + ab);
  uint4 ra1 = *(const uint4*)(pb + ab + 16);
#pragma nounroll
  for (int t = 0; t < md; t += 8) {
    uint4 rn0, rn1;
    if (t + 8 < md) {                           // wave-uniform branch
      rn0 = *(const uint4*)(pb + ab + 32);
      rn1 = *(const uint4*)(pb + ab + 48);
    } else {
      rn0 = ra0; rn1 = ra1;
    }
    unsigned ra[8] = {ra0.x, ra0.y, ra0.z, ra0.w, ra1.x, ra1.y, ra1.z, ra1.w};
    int rem = deg - t;
#pragma unroll
    for (int u = 0; u < 8; ++u) {
      unsigned r = ra[u];
      unsigned uidx = min(r >> 16, NMAX);
      float wv = (u < rem) ? rec_w(r) : 0.f;
      uint4 z = *(const uint4*)(zb + (uidx << 10) + cbyte);
      float f[8];
      unpack8(z, f);
#pragma unroll
      for (int i = 0; i < 8; ++i) acc[i] = fmaf(wv, f[i], acc[i]);
    }
    ra0 = rn0; ra1 = rn1;
    ab += 32;
  }

  if (bias) {
    const float4* b4 = (const float4*)(bias + slice * 64 + sub * 8);
    float4 b0 = b4[0], b1 = b4[1];
    acc[0] += b0.x; acc[1] += b0.y; acc[2] += b0.z; acc[3] += b0.w;
    acc[4] += b1.x; acc[5] += b1.y; acc[6] += b1.z; acc[7] += b1.w;
  }
  if (out_bf) {
    uint4 pv = pack8(acc);
    *(uint4*)((char*)out_bf + (((unsigned)v) << 10) + cbyte) = pv;
  } else {
    char* p = (char*)out_f32 + (((unsigned)v) << 11) + cbyte * 2;
    *(f32x4*)p = (f32x4){acc[0], acc[1], acc[2], acc[3]};
    *(f32x4*)(p + 16) = (f32x4){acc[4], acc[5], acc[6], acc[7]};
  }
}

// ================= launch =================
extern "C" void kernel_launch(void* const* d_in, const int* in_sizes, int n_in,
                              void* d_out, int out_size, void* d_ws, size_t ws_size,
                              hipStream_t stream) {
  const float* feat = (const float*)d_in[0];
  const float* fc_W = (const float*)d_in[1];
  const float* fc_b = (const float*)d_in[2];
  const float* gat_W = (const float*)d_in[3];
  const float* gat_al = (const float*)d_in[4];
  const float* gat_ar = (const float*)d_in[5];
  const float* gat_b = (const float*)d_in[6];
  // d_in[7] = beta unused (reference returns Z_prev)
  const int* src = (const int*)d_in[8];
  const int* dst = (const int*)d_in[9];
  float* out = (float*)d_out;

  char* w = (char*)d_ws;
  auto alloc = [&](size_t bytes) {
    char* p = w;
    w += (bytes + 255) & ~(size_t)255;
    return p;
  };
  unsigned short* hbf   = (unsigned short*)alloc((size_t)M_PAD * DIM_H * 2);
  unsigned short* fcWt  = (unsigned short*)alloc((size_t)DIM_H * DIM_IN * 2);
  unsigned short* gatWt = (unsigned short*)alloc((size_t)NUM_GNNS * DIM_H * DIM_H * 2);
  float* el    = (float*)alloc((size_t)N_NODES * 4);
  float* er    = (float*)alloc((size_t)N_NODES * 4);
  int* counts  = (int*)alloc((size_t)2 * N_NODES * 4);   // counts+cursor contiguous
  int* cursor  = counts + N_NODES;
  int* indptr  = (int*)alloc((size_t)(N_NODES + 1) * 4);
  int* adjsrc  = (int*)alloc((size_t)(N_EDGES + 64) * 4); // +pad for overshoot reads
  unsigned* onerec = (unsigned*)alloc((size_t)(N_EDGES + 64) * 4); // weight-1 records (+pad)
  int* perm    = (int*)alloc((size_t)N_NODES * 4);
  char* uni = alloc((size_t)M_PAD * DIM_IN * 2);   // 30.9 MB union region
  unsigned short* Abf = (unsigned short*)uni;      // live: convert + first GEMM only
  float* alpha = (float*)uni;                      // live: softmax scratch per layer (1.28 MB)
  unsigned short* Z1  = (unsigned short*)uni;      // live: propagation ping buffer (20.6 MB)
  // packed 4B alpha-records at uni+20.6MB: disjoint from Z1 AND from alpha
  unsigned* apairs = (unsigned*)(uni + (size_t)M_PAD * DIM_H * 2);  // 1.28 MB + pad
  unsigned short* zbf = (unsigned short*)d_out;

  // ---- CSR build + window-local degree sort ----
  hipMemsetAsync(counts, 0, sizeof(int) * 2 * N_NODES, stream);
  count_edges<<<(N_EDGES + 255) / 256, 256, 0, stream>>>(dst, counts);
  scan_kernel<<<1, 1024, 0, stream>>>(counts, indptr);
  fill_adj<<<(N_EDGES + 255) / 256, 256, 0, stream>>>(src, dst, indptr, cursor, adjsrc, onerec);
  build_perm_win<<<(N_NODES + 255) / 256, 256, 0, stream>>>(counts, perm);

  // ---- bf16 prep ----
  convert_feat<<<(M_PAD * DIM_IN / 8 + 255) / 256, 256, 0, stream>>>(feat, Abf);
  transpose_bf16<<<dim3(DIM_IN / 32, DIM_H / 32, 1), dim3(32, 8), 0, stream>>>(fc_W, fcWt, DIM_IN, DIM_H);
  transpose_bf16<<<dim3(DIM_H / 32, DIM_H / 32, NUM_GNNS), dim3(32, 8), 0, stream>>>(gat_W, gatWt, DIM_H, DIM_H);

  gemm_mfma_bf16<<<GEMM_GRID, 512, 0, stream>>>(Abf, fcWt, fc_b, hbf, DIM_IN);

  int nwaveblocks = (N_NODES * 64 + 255) / 256;
  for (int l = 0; l < NUM_GNNS; ++l) {
    gemm_mfma_bf16<<<GEMM_GRID, 512, 0, stream>>>(hbf, gatWt + (size_t)l * DIM_H * DIM_H,
                                                  nullptr, zbf, DIM_H);
    eler_bf<<<nwaveblocks, 256, 0, stream>>>(zbf, gat_al + (size_t)l * DIM_H,
                                             gat_ar + (size_t)l * DIM_H, el, er);
    edge_softmax_alpha<<<nwaveblocks, 256, 0, stream>>>(el, er, indptr, adjsrc, alpha, apairs);
    gather_slc<<<SLC_GRID, 256, 0, stream>>>(
        zbf, apairs, indptr, perm, gat_b + (size_t)l * DIM_H, 0, hbf, nullptr);
  }

  // ---- 3 propagation hops: weight-1 records written by fill_adj, same gather ----
  gather_slc<<<SLC_GRID, 256, 0, stream>>>(hbf, onerec, indptr, perm, nullptr, 1, Z1, nullptr);
  gather_slc<<<SLC_GRID, 256, 0, stream>>>(Z1, onerec, indptr, perm, nullptr, 1, hbf, nullptr);
  gather_slc<<<SLC_GRID, 256, 0, stream>>>(hbf, onerec, indptr, perm, nullptr, 1, nullptr, out);
}

// Round 16
// 542.730 us; speedup vs baseline: 1.0505x; 1.0147x over previous
//
#include <hip/hip_runtime.h>
#include <math.h>

#define N_NODES 20000
#define M_PAD   20096   // 157 * 128
#define N_EDGES 320000
#define DIM_IN 768
#define DIM_H 512
#define NUM_GNNS 4
#define NEG_SLOPE 0.2f

#define GEMM_TILES 628        // (M_PAD/128) * (DIM_H/128) = 157*4
#define GEMM_GRID  632        // ceil to multiple of 8 for XCD swizzle

// sliced gather: 8 column slices (64 cols), slice = bid&7 -> XCD (round-robin).
#define SLC_GRID 5000

typedef __attribute__((ext_vector_type(8))) short short8;
typedef __attribute__((ext_vector_type(4))) float f32x4;

#define GPTR(p) (const __attribute__((address_space(1))) void*)(p)
#define LPTR(p) (__attribute__((address_space(3))) void*)(p)

__device__ __forceinline__ float bf2f(unsigned int lo16) {
  return __uint_as_float(lo16 << 16);
}
__device__ __forceinline__ unsigned short f2bf(float f) {
  unsigned int u = __float_as_uint(f);
  u += 0x7FFFu + ((u >> 16) & 1u);   // round-to-nearest-even
  return (unsigned short)(u >> 16);
}
__device__ __forceinline__ void unpack8(uint4 v, float* f) {
  f[0] = bf2f(v.x & 0xffffu); f[1] = bf2f(v.x >> 16);
  f[2] = bf2f(v.y & 0xffffu); f[3] = bf2f(v.y >> 16);
  f[4] = bf2f(v.z & 0xffffu); f[5] = bf2f(v.z >> 16);
  f[6] = bf2f(v.w & 0xffffu); f[7] = bf2f(v.w >> 16);
}
__device__ __forceinline__ uint4 pack8(const float* o) {
  uint4 pv;
  pv.x = (unsigned)f2bf(o[0]) | ((unsigned)f2bf(o[1]) << 16);
  pv.y = (unsigned)f2bf(o[2]) | ((unsigned)f2bf(o[3]) << 16);
  pv.z = (unsigned)f2bf(o[4]) | ((unsigned)f2bf(o[5]) << 16);
  pv.w = (unsigned)f2bf(o[6]) | ((unsigned)f2bf(o[7]) << 16);
  return pv;
}

// packed (idx,weight) record: idx in high 16 bits, fp16 weight in low 16.
__device__ __forceinline__ unsigned pack_rec(int idx, float w) {
  unsigned short hb = __builtin_bit_cast(unsigned short, (_Float16)w);
  return ((unsigned)idx << 16) | (unsigned)hb;
}
__device__ __forceinline__ float rec_w(unsigned r) {
  return (float)__builtin_bit_cast(_Float16, (unsigned short)(r & 0xffffu));
}

__device__ __forceinline__ float waveReduceSum(float v) {
#pragma unroll
  for (int off = 32; off > 0; off >>= 1) v += __shfl_xor(v, off, 64);
  return v;
}
__device__ __forceinline__ float waveReduceMax(float v) {
#pragma unroll
  for (int off = 32; off > 0; off >>= 1) v = fmaxf(v, __shfl_xor(v, off, 64));
  return v;
}

// ============ MFMA GEMM: 128x128 tile, 8 waves (512 thr), dbuf LDS, coalesced C ============
__global__ __launch_bounds__(512) void gemm_mfma_bf16(
    const unsigned short* __restrict__ A,
    const unsigned short* __restrict__ Bt,
    const float* __restrict__ bias,
    unsigned short* __restrict__ Cbf,
    int K) {
  int bid = blockIdx.x;
  int tile = (bid & 7) * (GEMM_GRID / 8) + (bid >> 3);
  if (tile >= GEMM_TILES) return;
  int brow = tile >> 2;   // 0..156
  int bcol = tile & 3;    // 0..3

  __shared__ __align__(16) unsigned short lds[4][128 * 32];
  int tid = threadIdx.x;
  int wave = tid >> 6, lane = tid & 63;
  int wm = wave >> 2, wn = wave & 3;   // 2 x 4 wave grid -> 64x32 per wave

  int rl = tid >> 2;
  int c4 = tid & 3;
  int kc = c4 ^ ((rl >> 1) & 3);
  const unsigned short* gA = A + (size_t)(brow * 128 + rl) * K + kc * 8;
  const unsigned short* gB = Bt + (size_t)(bcol * 128 + rl) * K + kc * 8;
  int stgoff = 16 * wave * 32;   // shorts

  int mrow = lane & 15;
  int q = lane >> 4;
  int swz = (q ^ ((mrow >> 1) & 3)) * 8;

  f32x4 acc[4][2];
#pragma unroll
  for (int i = 0; i < 4; ++i)
#pragma unroll
    for (int j = 0; j < 2; ++j) acc[i][j] = (f32x4)(0.f);

  int nk = K >> 5;
  {
    __builtin_amdgcn_global_load_lds(GPTR(gA), LPTR(lds[0] + stgoff), 16, 0, 0);
    __builtin_amdgcn_global_load_lds(GPTR(gB), LPTR(lds[2] + stgoff), 16, 0, 0);
  }
  __syncthreads();

  for (int t = 0; t < nk; ++t) {
    int cur = t & 1;
    if (t + 1 < nk) {
      int k0 = (t + 1) << 5;
      __builtin_amdgcn_global_load_lds(GPTR(gA + k0), LPTR(lds[cur ^ 1] + stgoff), 16, 0, 0);
      __builtin_amdgcn_global_load_lds(GPTR(gB + k0), LPTR(lds[2 + (cur ^ 1)] + stgoff), 16, 0, 0);
    }
    const short8* ra = (const short8*)(lds[cur] + (64 * wm + mrow) * 32 + swz);
    const short8* rb = (const short8*)(lds[2 + cur] + (32 * wn + mrow) * 32 + swz);
    short8 a[4], b[2];
#pragma unroll
    for (int u = 0; u < 4; ++u) a[u] = ra[u * 64];
#pragma unroll
    for (int u = 0; u < 2; ++u) b[u] = rb[u * 64];
#pragma unroll
    for (int mt = 0; mt < 4; ++mt)
#pragma unroll
      for (int nt = 0; nt < 2; ++nt)
        acc[mt][nt] = __builtin_amdgcn_mfma_f32_16x16x32_bf16(a[mt], b[nt], acc[mt][nt], 0, 0, 0);
    __syncthreads();
  }

  unsigned short* Cs = &lds[0][0];
  {
    float bv[2];
#pragma unroll
    for (int nt = 0; nt < 2; ++nt)
      bv[nt] = bias ? bias[bcol * 128 + 32 * wn + 16 * nt + mrow] : 0.f;
#pragma unroll
    for (int mt = 0; mt < 4; ++mt)
#pragma unroll
      for (int nt = 0; nt < 2; ++nt)
#pragma unroll
        for (int i = 0; i < 4; ++i) {
          int row = 64 * wm + 16 * mt + 4 * q + i;
          int col = 32 * wn + 16 * nt + mrow;
          Cs[row * 128 + col] = f2bf(acc[mt][nt][i] + bv[nt]);
        }
  }
  __syncthreads();
  int rr = tid >> 4, cb = (tid & 15) * 8;
#pragma unroll
  for (int it = 0; it < 4; ++it, rr += 32) {
    uint4 val = *(const uint4*)(Cs + rr * 128 + cb);
    *(uint4*)(Cbf + (size_t)(brow * 128 + rr) * DIM_H + bcol * 128 + cb) = val;
  }
}

// ================= conversions =================
__global__ void convert_feat(const float* __restrict__ feat, unsigned short* __restrict__ Abf) {
  int t = blockIdx.x * blockDim.x + threadIdx.x;
  const int CHUNKS = M_PAD * DIM_IN / 8;
  if (t >= CHUNKS) return;
  int row = t / (DIM_IN / 8);
  uint4 o;
  if (row < N_NODES) {
    const float4* p = (const float4*)(feat + (size_t)t * 8);
    float4 x = p[0], y = p[1];
    o.x = (unsigned)f2bf(x.x) | ((unsigned)f2bf(x.y) << 16);
    o.y = (unsigned)f2bf(x.z) | ((unsigned)f2bf(x.w) << 16);
    o.z = (unsigned)f2bf(y.x) | ((unsigned)f2bf(y.y) << 16);
    o.w = (unsigned)f2bf(y.z) | ((unsigned)f2bf(y.w) << 16);
  } else {
    o = make_uint4(0, 0, 0, 0);
  }
  ((uint4*)Abf)[t] = o;
}

// LDS-tiled transpose: in [R,C] f32 -> out [C,R] bf16. R,C multiples of 32.
__global__ __launch_bounds__(256) void transpose_bf16(const float* __restrict__ in,
                                                      unsigned short* __restrict__ out,
                                                      int R, int C) {
  __shared__ float tile[32][33];
  int tx = threadIdx.x, ty = threadIdx.y;
  size_t base = (size_t)blockIdx.z * R * C;
  int r0 = blockIdx.x * 32, c0 = blockIdx.y * 32;
#pragma unroll
  for (int i = 0; i < 4; ++i) {
    int r = r0 + ty + i * 8;
    tile[ty + i * 8][tx] = in[base + (size_t)r * C + c0 + tx];
  }
  __syncthreads();
#pragma unroll
  for (int i = 0; i < 4; ++i) {
    int c = c0 + ty + i * 8;
    out[base + (size_t)c * R + r0 + tx] = f2bf(tile[tx][ty + i * 8]);
  }
}

// ================= CSR build (dst -> src adjacency) =================
__global__ void count_edges(const int* __restrict__ dst, int* __restrict__ counts) {
  int k = blockIdx.x * blockDim.x + threadIdx.x;
  if (k < N_EDGES) atomicAdd(&counts[dst[k]], 1);
}

__global__ __launch_bounds__(1024) void scan_kernel(const int* __restrict__ counts,
                                                    int* __restrict__ indptr) {
  __shared__ int part[1024];
  int tid = threadIdx.x;
  const int CH = (N_NODES + 1023) / 1024;
  int base = tid * CH;
  int s = 0;
  for (int i = 0; i < CH; ++i) {
    int idx = base + i;
    if (idx < N_NODES) s += counts[idx];
  }
  part[tid] = s;
  __syncthreads();
  for (int off = 1; off < 1024; off <<= 1) {
    int v = (tid >= off) ? part[tid - off] : 0;
    __syncthreads();
    part[tid] += v;
    __syncthreads();
  }
  int run = (tid == 0) ? 0 : part[tid - 1];
  for (int i = 0; i < CH; ++i) {
    int idx = base + i;
    if (idx < N_NODES) {
      indptr[idx] = run;
      run += counts[idx];
      if (idx == N_NODES - 1) indptr[N_NODES] = run;
    }
  }
}

__global__ void fill_adj(const int* __restrict__ src, const int* __restrict__ dst,
                         const int* __restrict__ indptr, int* __restrict__ cursor,
                         int* __restrict__ adjsrc) {
  int k = blockIdx.x * blockDim.x + threadIdx.x;
  if (k < N_EDGES) {
    int d = dst[k];
    int pos = atomicAdd(&cursor[d], 1);
    adjsrc[indptr[d] + pos] = src[k];
  }
}

// ============ window-local degree sort (256-node windows, LDS counting sort) ============
__global__ __launch_bounds__(256) void build_perm_win(const int* __restrict__ counts,
                                                      int* __restrict__ perm) {
  __shared__ int hist[64];
  __shared__ int basec[64];
  int tid = threadIdx.x;
  int v0 = blockIdx.x * 256;
  int n = min(256, N_NODES - v0);
  if (tid < 64) hist[tid] = 0;
  __syncthreads();
  int b = 0;
  if (tid < n) {
    b = min(counts[v0 + tid], 63);
    atomicAdd(&hist[b], 1);
  }
  __syncthreads();
  if (tid == 0) {
    int run = 0;
#pragma unroll
    for (int i = 0; i < 64; ++i) { basec[i] = run; run += hist[i]; }
  }
  __syncthreads();
  if (tid < n) {
    int pos = atomicAdd(&basec[b], 1);
    perm[v0 + pos] = v0 + tid;
  }
}

// ============ weight-1 packed records for propagation hops ============
__global__ void pack_ones(const int* __restrict__ adjsrc, unsigned* __restrict__ apairs) {
  int k = blockIdx.x * blockDim.x + threadIdx.x;
  if (k < N_EDGES) apairs[k] = ((unsigned)adjsrc[k] << 16) | 0x3C00u;  // fp16 1.0
}

// ================= el/er from bf16 z =================
__global__ __launch_bounds__(256) void eler_bf(const unsigned short* __restrict__ zbf,
                                               const float* __restrict__ al,
                                               const float* __restrict__ ar,
                                               float* __restrict__ el, float* __restrict__ er) {
  int wid = (blockIdx.x * blockDim.x + threadIdx.x) >> 6;
  int lane = threadIdx.x & 63;
  if (wid >= N_NODES) return;
  uint4 zv = ((const uint4*)(zbf + (size_t)wid * DIM_H))[lane];
  float z[8];
  unpack8(zv, z);
  const float4* al4 = (const float4*)(al + lane * 8);
  const float4* ar4 = (const float4*)(ar + lane * 8);
  float4 a0 = al4[0], a1 = al4[1], r0 = ar4[0], r1 = ar4[1];
  float sl = z[0] * a0.x + z[1] * a0.y + z[2] * a0.z + z[3] * a0.w +
             z[4] * a1.x + z[5] * a1.y + z[6] * a1.z + z[7] * a1.w;
  float sr = z[0] * r0.x + z[1] * r0.y + z[2] * r0.z + z[3] * r0.w +
             z[4] * r1.x + z[5] * r1.y + z[6] * r1.z + z[7] * r1.w;
  sl = waveReduceSum(sl);
  sr = waveReduceSum(sr);
  if (lane == 0) { el[wid] = sl; er[wid] = sr; }
}

// ================= edge softmax -> packed uint32 (idx<<16 | fp16 alpha) records =========
__global__ __launch_bounds__(256) void edge_softmax_alpha(
    const float* __restrict__ el, const float* __restrict__ er,
    const int* __restrict__ indptr, const int* __restrict__ adjsrc,
    float* __restrict__ alpha, unsigned* __restrict__ apairs) {
  int v = (blockIdx.x * blockDim.x + threadIdx.x) >> 6;
  int lane = threadIdx.x & 63;
  if (v >= N_NODES) return;
  int begin = indptr[v], end = indptr[v + 1];
  float er_v = er[v];

  float m = -INFINITY;
  for (int j = begin + lane; j < end; j += 64) {
    float e = el[adjsrc[j]] + er_v;
    e = (e >= 0.f) ? e : NEG_SLOPE * e;
    alpha[j] = e;
    m = fmaxf(m, e);
  }
  m = waveReduceMax(m);

  float ss = 0.f;
  for (int j = begin + lane; j < end; j += 64) {
    float ex = __expf(alpha[j] - m);
    alpha[j] = ex;
    ss += ex;
  }
  float denom = waveReduceSum(ss);
  float inv = (end > begin) ? 1.f / denom : 0.f;

  for (int j = begin + lane; j < end; j += 64)
    apairs[j] = pack_rec(adjsrc[j], alpha[j] * inv);
}

// ========== XCD-sliced gather: slot-per-node (window-sorted), 4B records, prefetch =======
__global__ __launch_bounds__(256) void gather_slc(
    const unsigned short* __restrict__ zin, const unsigned* __restrict__ apairs,
    const int* __restrict__ indptr, const int* __restrict__ perm,
    const float* __restrict__ bias, int self_term,
    unsigned short* __restrict__ out_bf, float* __restrict__ out_f32) {
  int slice = blockIdx.x & 7;
  int grp = blockIdx.x >> 3;                    // 0..624
  int wave = threadIdx.x >> 6, lane = threadIdx.x & 63;
  int slot = lane >> 3, sub = lane & 7;
  int vidx = grp * 32 + wave * 8 + slot;
  int v = perm[vidx];                           // window-degree-sorted node
  unsigned cbyte = (unsigned)(slice * 128 + sub * 16);
  const char* zb = (const char*)zin;
  const char* pb = (const char*)apairs;

  int b = indptr[v];
  int deg = indptr[v + 1] - b;
  int md = deg;                                 // max degree over the 8 slots (~deg now)
  md = max(md, __shfl_xor(md, 8, 64));
  md = max(md, __shfl_xor(md, 16, 64));
  md = max(md, __shfl_xor(md, 32, 64));

  float acc[8];
  if (self_term) {
    uint4 sz = *(const uint4*)(zb + (((unsigned)v) << 10) + cbyte);
    unpack8(sz, acc);
  } else {
#pragma unroll
    for (int i = 0; i < 8; ++i) acc[i] = 0.f;
  }

  const unsigned NMAX = (unsigned)(N_NODES - 1);
  unsigned ab = ((unsigned)b) << 2;             // 4B records
  uint4 ra0 = *(const uint4*)(pb + ab);
  uint4 ra1 = *(const uint4*)(pb + ab + 16);
#pragma nounroll
  for (int t = 0; t < md; t += 8) {
    uint4 rn0, rn1;
    if (t + 8 < md) {                           // wave-uniform branch
      rn0 = *(const uint4*)(pb + ab + 32);
      rn1 = *(const uint4*)(pb + ab + 48);
    } else {
      rn0 = ra0; rn1 = ra1;
    }
    unsigned ra[8] = {ra0.x, ra0.y, ra0.z, ra0.w, ra1.x, ra1.y, ra1.z, ra1.w};
    int rem = deg - t;
#pragma unroll
    for (int u = 0; u < 8; ++u) {
      unsigned r = ra[u];
      unsigned uidx = min(r >> 16, NMAX);
      float wv = (u < rem) ? rec_w(r) : 0.f;
      uint4 z = *(const uint4*)(zb + (uidx << 10) + cbyte);
      float f[8];
      unpack8(z, f);
#pragma unroll
      for (int i = 0; i < 8; ++i) acc[i] = fmaf(wv, f[i], acc[i]);
    }
    ra0 = rn0; ra1 = rn1;
    ab += 32;
  }

  if (bias) {
    const float4* b4 = (const float4*)(bias + slice * 64 + sub * 8);
    float4 b0 = b4[0], b1 = b4[1];
    acc[0] += b0.x; acc[1] += b0.y; acc[2] += b0.z; acc[3] += b0.w;
    acc[4] += b1.x; acc[5] += b1.y; acc[6] += b1.z; acc[7] += b1.w;
  }
  if (out_bf) {
    uint4 pv = pack8(acc);
    *(uint4*)((char*)out_bf + (((unsigned)v) << 10) + cbyte) = pv;
  } else {
    char* p = (char*)out_f32 + (((unsigned)v) << 11) + cbyte * 2;
    *(f32x4*)p = (f32x4){acc[0], acc[1], acc[2], acc[3]};
    *(f32x4*)(p + 16) = (f32x4){acc[4], acc[5], acc[6], acc[7]};
  }
}

// ================= launch =================
extern "C" void kernel_launch(void* const* d_in, const int* in_sizes, int n_in,
                              void* d_out, int out_size, void* d_ws, size_t ws_size,
                              hipStream_t stream) {
  const float* feat = (const float*)d_in[0];
  const float* fc_W = (const float*)d_in[1];
  const float* fc_b = (const float*)d_in[2];
  const float* gat_W = (const float*)d_in[3];
  const float* gat_al = (const float*)d_in[4];
  const float* gat_ar = (const float*)d_in[5];
  const float* gat_b = (const float*)d_in[6];
  // d_in[7] = beta unused (reference returns Z_prev)
  const int* src = (const int*)d_in[8];
  const int* dst = (const int*)d_in[9];
  float* out = (float*)d_out;

  char* w = (char*)d_ws;
  auto alloc = [&](size_t bytes) {
    char* p = w;
    w += (bytes + 255) & ~(size_t)255;
    return p;
  };
  unsigned short* hbf   = (unsigned short*)alloc((size_t)M_PAD * DIM_H * 2);
  unsigned short* fcWt  = (unsigned short*)alloc((size_t)DIM_H * DIM_IN * 2);
  unsigned short* gatWt = (unsigned short*)alloc((size_t)NUM_GNNS * DIM_H * DIM_H * 2);
  float* el    = (float*)alloc((size_t)N_NODES * 4);
  float* er    = (float*)alloc((size_t)N_NODES * 4);
  int* counts  = (int*)alloc((size_t)2 * N_NODES * 4);   // counts+cursor contiguous
  int* cursor  = counts + N_NODES;
  int* indptr  = (int*)alloc((size_t)(N_NODES + 1) * 4);
  int* adjsrc  = (int*)alloc((size_t)(N_EDGES + 64) * 4); // +pad for overshoot reads
  int* perm    = (int*)alloc((size_t)N_NODES * 4);
  char* uni = alloc((size_t)M_PAD * DIM_IN * 2);   // 30.9 MB union region
  unsigned short* Abf = (unsigned short*)uni;      // live: convert + first GEMM only
  float* alpha = (float*)uni;                      // live: softmax scratch per layer (1.28 MB)
  unsigned short* Z1  = (unsigned short*)uni;      // live: propagation ping buffer (20.6 MB)
  // packed 4B records at uni+20.6MB: disjoint from Z1 AND from alpha
  unsigned* apairs = (unsigned*)(uni + (size_t)M_PAD * DIM_H * 2);  // 1.28 MB + pad
  unsigned short* zbf = (unsigned short*)d_out;

  // ---- CSR build + window-local degree sort ----
  hipMemsetAsync(counts, 0, sizeof(int) * 2 * N_NODES, stream);
  count_edges<<<(N_EDGES + 255) / 256, 256, 0, stream>>>(dst, counts);
  scan_kernel<<<1, 1024, 0, stream>>>(counts, indptr);
  fill_adj<<<(N_EDGES + 255) / 256, 256, 0, stream>>>(src, dst, indptr, cursor, adjsrc);
  build_perm_win<<<(N_NODES + 255) / 256, 256, 0, stream>>>(counts, perm);

  // ---- bf16 prep ----
  convert_feat<<<(M_PAD * DIM_IN / 8 + 255) / 256, 256, 0, stream>>>(feat, Abf);
  transpose_bf16<<<dim3(DIM_IN / 32, DIM_H / 32, 1), dim3(32, 8), 0, stream>>>(fc_W, fcWt, DIM_IN, DIM_H);
  transpose_bf16<<<dim3(DIM_H / 32, DIM_H / 32, NUM_GNNS), dim3(32, 8), 0, stream>>>(gat_W, gatWt, DIM_H, DIM_H);

  gemm_mfma_bf16<<<GEMM_GRID, 512, 0, stream>>>(Abf, fcWt, fc_b, hbf, DIM_IN);

  int nwaveblocks = (N_NODES * 64 + 255) / 256;
  for (int l = 0; l < NUM_GNNS; ++l) {
    gemm_mfma_bf16<<<GEMM_GRID, 512, 0, stream>>>(hbf, gatWt + (size_t)l * DIM_H * DIM_H,
                                                  nullptr, zbf, DIM_H);
    eler_bf<<<nwaveblocks, 256, 0, stream>>>(zbf, gat_al + (size_t)l * DIM_H,
                                             gat_ar + (size_t)l * DIM_H, el, er);
    edge_softmax_alpha<<<nwaveblocks, 256, 0, stream>>>(el, er, indptr, adjsrc, alpha, apairs);
    gather_slc<<<SLC_GRID, 256, 0, stream>>>(
        zbf, apairs, indptr, perm, gat_b + (size_t)l * DIM_H, 0, hbf, nullptr);
  }

  // ---- 3 propagation hops: weight-1 packed records, same gather ----
  pack_ones<<<(N_EDGES + 255) / 256, 256, 0, stream>>>(adjsrc, apairs);
  gather_slc<<<SLC_GRID, 256, 0, stream>>>(hbf, apairs, indptr, perm, nullptr, 1, Z1, nullptr);
  gather_slc<<<SLC_GRID, 256, 0, stream>>>(Z1, apairs, indptr, perm, nullptr, 1, hbf, nullptr);
  gather_slc<<<SLC_GRID, 256, 0, stream>>>(hbf, apairs, indptr, perm, nullptr, 1, nullptr, out);
}